// Round 5
// baseline (97.283 us; speedup 1.0000x reference)
//
#include <hip/hip_runtime.h>
#include <hip/hip_bf16.h>

// MMD loss, atomic-free, bf16 MFMA Gram. Tile 128x128, BK=128 (2 K-steps),
// 64KB LDS single-buffered -> 2 blocks/CU so staging of one block overlaps
// MFMA of the other.
//
// ws layout (float offsets):
//  [2]                 c2 = -log2(e)/(16*bw)
//  SQ_OFF   = 4        sq norms [8192] (0..4095 src, 4096..8191 tgt)
//  S1PART   = 8196     per-block sum-of-norms partials [128]
//  CROSSPART= 8324     per-block cross partials [1024]
//  COLPART  = 9348     per-block colsum partials [128][256]
//  ABF_OFF  = 42116    src as bf16 [4096*256]
//  BBF_OFF  = 566404   tgt as bf16 [4096*256]

#define D 256
#define NROWS 4096
#define SQ_OFF 4
#define S1PART 8196
#define CROSSPART 8324
#define COLPART 9348
#define ABF_OFF 42116
#define BBF_OFF 566404
#define WS_NEED_FLOATS 1090692

typedef __attribute__((ext_vector_type(8))) short short8;
typedef __attribute__((ext_vector_type(16))) float float16;
typedef unsigned short ushort_t;

__device__ inline unsigned pack2_bf16(float a, float b) {
  unsigned ua = __float_as_uint(a);
  ua += 0x7FFFu + ((ua >> 16) & 1u);
  unsigned ub = __float_as_uint(b);
  ub += 0x7FFFu + ((ub >> 16) & 1u);
  return (ua >> 16) | (ub & 0xFFFF0000u);
}

__device__ inline void gload_lds16(const ushort_t* g, ushort_t* l) {
  __builtin_amdgcn_global_load_lds(
      (const __attribute__((address_space(1))) unsigned int*)g,
      (__attribute__((address_space(3))) unsigned int*)l, 16, 0, 0);
}

__global__ __launch_bounds__(256) void prep_kernel(const float* __restrict__ src,
                                                   const float* __restrict__ tgt,
                                                   float* __restrict__ ws,
                                                   int writeBf16) {
  __shared__ float csL[4][256];
  __shared__ float s1L[4];
  ushort_t* Abf = (ushort_t*)(ws + ABF_OFF);
  ushort_t* Bbf = (ushort_t*)(ws + BBF_OFF);
  int t = threadIdx.x;
  int wave = t >> 6, lane = t & 63;
  int rowBase = blockIdx.x * 64 + wave * 16;
  float cs0 = 0.f, cs1 = 0.f, cs2 = 0.f, cs3 = 0.f, s1 = 0.f;
  for (int r = 0; r < 16; ++r) {
    int row = rowBase + r;
    int isA = row < NROWS;
    const float* p = isA ? (src + (size_t)row * D) : (tgt + (size_t)(row - NROWS) * D);
    float4 v = reinterpret_cast<const float4*>(p)[lane];
    if (writeBf16) {
      ushort_t* dst = (isA ? Abf + (size_t)row * D : Bbf + (size_t)(row - NROWS) * D) + lane * 4;
      *reinterpret_cast<uint2*>(dst) = make_uint2(pack2_bf16(v.x, v.y), pack2_bf16(v.z, v.w));
    }
    cs0 += v.x; cs1 += v.y; cs2 += v.z; cs3 += v.w;
    float sq = v.x * v.x + v.y * v.y + v.z * v.z + v.w * v.w;
#pragma unroll
    for (int off = 32; off; off >>= 1) sq += __shfl_xor(sq, off, 64);
    if (lane == 0) { ws[SQ_OFF + row] = sq; s1 += sq; }
  }
  csL[wave][lane * 4 + 0] = cs0;
  csL[wave][lane * 4 + 1] = cs1;
  csL[wave][lane * 4 + 2] = cs2;
  csL[wave][lane * 4 + 3] = cs3;
  if (lane == 0) s1L[wave] = s1;
  __syncthreads();
  ws[COLPART + blockIdx.x * 256 + t] = csL[0][t] + csL[1][t] + csL[2][t] + csL[3][t];
  if (t == 0) ws[S1PART + blockIdx.x] = s1L[0] + s1L[1] + s1L[2] + s1L[3];
}

__global__ __launch_bounds__(256) void bw_kernel(float* __restrict__ ws) {
  __shared__ float red[256];
  __shared__ float s1red[128];
  int t = threadIdx.x;
  float colsum = 0.f;
#pragma unroll 8
  for (int b = 0; b < 128; ++b) colsum += ws[COLPART + b * 256 + t];
  red[t] = colsum * colsum;
  if (t < 128) s1red[t] = ws[S1PART + t];
  __syncthreads();
#pragma unroll
  for (int s = 128; s > 0; s >>= 1) {
    if (t < s) red[t] += red[t + s];
    if (s > 1 && t < (s >> 1)) s1red[t] += s1red[t + (s >> 1)];
    __syncthreads();
  }
  if (t == 0) {
    double n = 8192.0;
    double sumL2 = 2.0 * n * (double)s1red[0] - 2.0 * (double)red[0];
    double bw = sumL2 / (n * n - n) / 4.0;  // KERNEL_MUL^(KERNEL_NUM//2) = 4
    ws[2] = (float)(-1.4426950408889634 / (16.0 * bw));
  }
}

// LDS tile rows = 128 bf16 = 256B = 16 chunks of 16B.
// Swizzle: chunk slot s of row r holds global chunk s ^ (r&7).
template <int BF16SRC>
__global__ __launch_bounds__(256) void cross_kernel(const float* __restrict__ A32,
                                                    const float* __restrict__ B32,
                                                    const ushort_t* __restrict__ Abf,
                                                    const ushort_t* __restrict__ Bbf,
                                                    float* __restrict__ ws) {
  __shared__ ushort_t Abuf[128 * 128];  // 32 KB
  __shared__ ushort_t Bbuf[128 * 128];  // 32 KB
  __shared__ float sqAs[128], sqBs[128];
  __shared__ float red[256];
  int t = threadIdx.x;
  int bid = blockIdx.x;
  // XCD-aware 2D chunking: each XCD owns an 8x16 rectangle of 128^2 tiles
  int xcd = bid & 7, q = bid >> 3;
  int bi = (xcd >> 1) * 8 + (q >> 4);
  int bj = (xcd & 1) * 16 + (q & 15);
  int rowBase = bi * 128, colBase = bj * 128;
  int wave = t >> 6, lane = t & 63;
  int wm = wave >> 1, wn = wave & 1;
  int hi = lane >> 5;
  int lr = lane & 31;
  int sr = t >> 4, sc = t & 15;  // fallback staging coords

  if (t < 128) sqAs[t] = ws[SQ_OFF + rowBase + t];
  else         sqBs[t - 128] = ws[SQ_OFF + NROWS + colBase + (t - 128)];

  float16 acc00, acc01, acc10, acc11;
#pragma unroll
  for (int r = 0; r < 16; ++r) { acc00[r] = 0.f; acc01[r] = 0.f; acc10[r] = 0.f; acc11[r] = 0.f; }

  // gload staging geometry: one instr = 64 lanes x 16B = 4 rows of 256B.
  int grow = lane >> 4;                 // row offset within 4-row batch
  int gslot = lane & 15;                // LDS chunk slot
  for (int k0 = 0; k0 < D; k0 += 128) {
    if (BF16SRC) {
      int w32 = wave * 32;
#pragma unroll
      for (int j = 0; j < 8; ++j) {
        int r0 = w32 + j * 4;
        int row = r0 + grow;
        int ca = gslot ^ (row & 7);     // inverse-swizzled global chunk
        gload_lds16(Abf + (size_t)(rowBase + row) * D + k0 + ca * 8, &Abuf[r0 * 128]);
        gload_lds16(Bbf + (size_t)(colBase + row) * D + k0 + ca * 8, &Bbuf[r0 * 128]);
      }
    } else {
#pragma unroll
      for (int i = 0; i < 8; ++i) {
        int r = sr + 16 * i;
        int slot = (sc ^ (r & 7)) * 8;  // ushort units
        const float* pa = &A32[(size_t)(rowBase + r) * D + k0 + sc * 8];
        float4 va0 = *reinterpret_cast<const float4*>(pa);
        float4 va1 = *reinterpret_cast<const float4*>(pa + 4);
        uint4 wa = make_uint4(pack2_bf16(va0.x, va0.y), pack2_bf16(va0.z, va0.w),
                              pack2_bf16(va1.x, va1.y), pack2_bf16(va1.z, va1.w));
        *reinterpret_cast<uint4*>(&Abuf[r * 128 + slot]) = wa;
        const float* pb = &B32[(size_t)(colBase + r) * D + k0 + sc * 8];
        float4 vb0 = *reinterpret_cast<const float4*>(pb);
        float4 vb1 = *reinterpret_cast<const float4*>(pb + 4);
        uint4 wb = make_uint4(pack2_bf16(vb0.x, vb0.y), pack2_bf16(vb0.z, vb0.w),
                              pack2_bf16(vb1.x, vb1.y), pack2_bf16(vb1.z, vb1.w));
        *reinterpret_cast<uint4*>(&Bbuf[r * 128 + slot]) = wb;
      }
    }
    __syncthreads();  // drains vmcnt (global_load_lds) + lgkm
#pragma unroll
    for (int ks = 0; ks < 8; ++ks) {
      int c0 = ks * 2 + hi;  // 16B chunk within 256B row
      int ra0 = wm * 64 + lr, ra1 = ra0 + 32;
      int rb0 = wn * 64 + lr, rb1 = rb0 + 32;
      short8 a0 = *reinterpret_cast<const short8*>(&Abuf[ra0 * 128 + ((c0 ^ (ra0 & 7)) << 3)]);
      short8 a1 = *reinterpret_cast<const short8*>(&Abuf[ra1 * 128 + ((c0 ^ (ra1 & 7)) << 3)]);
      short8 b0 = *reinterpret_cast<const short8*>(&Bbuf[rb0 * 128 + ((c0 ^ (rb0 & 7)) << 3)]);
      short8 b1 = *reinterpret_cast<const short8*>(&Bbuf[rb1 * 128 + ((c0 ^ (rb1 & 7)) << 3)]);
      acc00 = __builtin_amdgcn_mfma_f32_32x32x16_bf16(a0, b0, acc00, 0, 0, 0);
      acc01 = __builtin_amdgcn_mfma_f32_32x32x16_bf16(a0, b1, acc01, 0, 0, 0);
      acc10 = __builtin_amdgcn_mfma_f32_32x32x16_bf16(a1, b0, acc10, 0, 0, 0);
      acc11 = __builtin_amdgcn_mfma_f32_32x32x16_bf16(a1, b1, acc11, 0, 0, 0);
    }
    __syncthreads();
  }

  // Epilogue: C/D layout col=lane&31, row=(reg&3)+8*(reg>>2)+4*(lane>>5)  [m74/m101]
  float c2 = ws[2];
  float local = 0.f;
#pragma unroll
  for (int m2 = 0; m2 < 2; ++m2) {
#pragma unroll
    for (int n2 = 0; n2 < 2; ++n2) {
      const float16& g = (m2 == 0) ? ((n2 == 0) ? acc00 : acc01)
                                   : ((n2 == 0) ? acc10 : acc11);
      float sB = sqBs[wn * 64 + n2 * 32 + lr];
#pragma unroll
      for (int r = 0; r < 16; ++r) {
        int row = (r & 3) + 8 * (r >> 2) + 4 * hi;
        float dd = sqAs[wm * 64 + m2 * 32 + row] + sB - 2.0f * g[r];
        float y = __builtin_amdgcn_exp2f(dd * c2);  // exp(-d/(16 bw))
        float y2 = y * y, y4 = y2 * y2, y8 = y4 * y4, y16 = y8 * y8;
        local += y + y2 + y4 + y8 + y16;
      }
    }
  }
  red[t] = local;
  __syncthreads();
#pragma unroll
  for (int s = 128; s > 0; s >>= 1) {
    if (t < s) red[t] += red[t + s];
    __syncthreads();
  }
  if (t == 0) ws[CROSSPART + bid] = red[0];
}

__global__ __launch_bounds__(256) void finalize_kernel(const float* __restrict__ ws,
                                                       float* __restrict__ out) {
  __shared__ float red[256];
  int t = threadIdx.x;
  red[t] = ws[CROSSPART + t] + ws[CROSSPART + 256 + t] +
           ws[CROSSPART + 512 + t] + ws[CROSSPART + 768 + t];
  __syncthreads();
#pragma unroll
  for (int s = 128; s > 0; s >>= 1) {
    if (t < s) red[t] += red[t + s];
    __syncthreads();
  }
  if (t == 0) out[0] = -2.0f * (red[0] * (1.0f / 16777216.0f));
}

extern "C" void kernel_launch(void* const* d_in, const int* in_sizes, int n_in,
                              void* d_out, int out_size, void* d_ws, size_t ws_size,
                              hipStream_t stream) {
  const float* src = (const float*)d_in[0];
  const float* tgt = (const float*)d_in[1];
  float* ws = (float*)d_ws;
  float* out = (float*)d_out;
  int useBf16 = ws_size >= (size_t)WS_NEED_FLOATS * sizeof(float);
  const ushort_t* Abf = (const ushort_t*)(ws + ABF_OFF);
  const ushort_t* Bbf = (const ushort_t*)(ws + BBF_OFF);

  prep_kernel<<<128, 256, 0, stream>>>(src, tgt, ws, useBf16);
  bw_kernel<<<1, 256, 0, stream>>>(ws);
  if (useBf16)
    cross_kernel<1><<<1024, 256, 0, stream>>>(src, tgt, Abf, Bbf, ws);
  else
    cross_kernel<0><<<1024, 256, 0, stream>>>(src, tgt, Abf, Bbf, ws);
  finalize_kernel<<<1, 256, 0, stream>>>(ws, out);
}

// Round 6
// 96.472 us; speedup vs baseline: 1.0084x; 1.0084x over previous
//
#include <hip/hip_runtime.h>
#include <hip/hip_bf16.h>

// MMD loss, atomic-free. Cross Gram: 256x256 tiles (256 blocks = 1/CU), 512 thr,
// BK=64, double-buffered LDS 2-phase prefetch pipeline, bf16 MFMA 32x32x16.
//
// ws layout (float offsets):
//  [2]                 c2 = -log2(e)/(16*bw)
//  SQ_OFF   = 4        sq norms [8192] (0..4095 src, 4096..8191 tgt)
//  S1PART   = 8196     per-block sum-of-norms partials [128]
//  CROSSPART= 8324     per-block cross partials [256]
//  COLPART  = 9348     per-block colsum partials [128][256]
//  ABF_OFF  = 42116    src as bf16 [4096*256]
//  BBF_OFF  = 566404   tgt as bf16 [4096*256]

#define D 256
#define NROWS 4096
#define SQ_OFF 4
#define S1PART 8196
#define CROSSPART 8324
#define COLPART 9348
#define ABF_OFF 42116
#define BBF_OFF 566404
#define WS_NEED_FLOATS 1090692

typedef __attribute__((ext_vector_type(8))) short short8;
typedef __attribute__((ext_vector_type(16))) float float16;
typedef unsigned short ushort_t;

__device__ inline unsigned pack2_bf16(float a, float b) {
  unsigned ua = __float_as_uint(a);
  ua += 0x7FFFu + ((ua >> 16) & 1u);
  unsigned ub = __float_as_uint(b);
  ub += 0x7FFFu + ((ub >> 16) & 1u);
  return (ua >> 16) | (ub & 0xFFFF0000u);
}

__device__ inline void gload_lds16(const ushort_t* g, ushort_t* l) {
  __builtin_amdgcn_global_load_lds(
      (const __attribute__((address_space(1))) unsigned int*)g,
      (__attribute__((address_space(3))) unsigned int*)l, 16, 0, 0);
}

__global__ __launch_bounds__(256) void prep_kernel(const float* __restrict__ src,
                                                   const float* __restrict__ tgt,
                                                   float* __restrict__ ws,
                                                   int writeBf16) {
  __shared__ float csL[4][256];
  __shared__ float s1L[4];
  ushort_t* Abf = (ushort_t*)(ws + ABF_OFF);
  ushort_t* Bbf = (ushort_t*)(ws + BBF_OFF);
  int t = threadIdx.x;
  int wave = t >> 6, lane = t & 63;
  int rowBase = blockIdx.x * 64 + wave * 16;
  float cs0 = 0.f, cs1 = 0.f, cs2 = 0.f, cs3 = 0.f, s1 = 0.f;
  for (int r = 0; r < 16; ++r) {
    int row = rowBase + r;
    int isA = row < NROWS;
    const float* p = isA ? (src + (size_t)row * D) : (tgt + (size_t)(row - NROWS) * D);
    float4 v = reinterpret_cast<const float4*>(p)[lane];
    if (writeBf16) {
      ushort_t* dst = (isA ? Abf + (size_t)row * D : Bbf + (size_t)(row - NROWS) * D) + lane * 4;
      *reinterpret_cast<uint2*>(dst) = make_uint2(pack2_bf16(v.x, v.y), pack2_bf16(v.z, v.w));
    }
    cs0 += v.x; cs1 += v.y; cs2 += v.z; cs3 += v.w;
    float sq = v.x * v.x + v.y * v.y + v.z * v.z + v.w * v.w;
#pragma unroll
    for (int off = 32; off; off >>= 1) sq += __shfl_xor(sq, off, 64);
    if (lane == 0) { ws[SQ_OFF + row] = sq; s1 += sq; }
  }
  csL[wave][lane * 4 + 0] = cs0;
  csL[wave][lane * 4 + 1] = cs1;
  csL[wave][lane * 4 + 2] = cs2;
  csL[wave][lane * 4 + 3] = cs3;
  if (lane == 0) s1L[wave] = s1;
  __syncthreads();
  ws[COLPART + blockIdx.x * 256 + t] = csL[0][t] + csL[1][t] + csL[2][t] + csL[3][t];
  if (t == 0) ws[S1PART + blockIdx.x] = s1L[0] + s1L[1] + s1L[2] + s1L[3];
}

__global__ __launch_bounds__(256) void bw_kernel(float* __restrict__ ws) {
  __shared__ float red[256];
  __shared__ float s1red[128];
  int t = threadIdx.x;
  float colsum = 0.f;
#pragma unroll 8
  for (int b = 0; b < 128; ++b) colsum += ws[COLPART + b * 256 + t];
  red[t] = colsum * colsum;
  if (t < 128) s1red[t] = ws[S1PART + t];
  __syncthreads();
#pragma unroll
  for (int s = 128; s > 0; s >>= 1) {
    if (t < s) red[t] += red[t + s];
    if (s > 1 && t < (s >> 1)) s1red[t] += s1red[t + (s >> 1)];
    __syncthreads();
  }
  if (t == 0) {
    double n = 8192.0;
    double sumL2 = 2.0 * n * (double)s1red[0] - 2.0 * (double)red[0];
    double bw = sumL2 / (n * n - n) / 4.0;  // KERNEL_MUL^(KERNEL_NUM//2) = 4
    ws[2] = (float)(-1.4426950408889634 / (16.0 * bw));
  }
}

// Cross tile 256x256, BK=64. LDS row = 64 bf16 = 128B = 8 chunks of 16B.
// Swizzle: chunk slot s of row r holds global chunk s ^ (r&7).
template <int BF16SRC>
__global__ __launch_bounds__(512, 2) void cross_kernel(const float* __restrict__ A32,
                                                       const float* __restrict__ B32,
                                                       const ushort_t* __restrict__ Abf,
                                                       const ushort_t* __restrict__ Bbf,
                                                       float* __restrict__ ws) {
  __shared__ ushort_t Ab[2][256 * 64];  // 2 x 32 KB
  __shared__ ushort_t Bb[2][256 * 64];  // 2 x 32 KB
  __shared__ float sqAs[256], sqBs[256];
  __shared__ float red[8];
  int t = threadIdx.x;
  int bid = blockIdx.x;
  // XCD-aware: 16x16 tile grid; each XCD owns a 4x8 rectangle (A 0.5MB + B 1MB bf16 in its L2)
  int xcd = bid & 7, idx = bid >> 3;
  int bi = (xcd >> 1) * 4 + (idx >> 3);
  int bj = (xcd & 1) * 8 + (idx & 7);
  int rowBase = bi * 256, colBase = bj * 256;
  int wave = t >> 6, lane = t & 63;
  int wm = wave >> 2, wn = wave & 3;   // 2x4 wave grid; wave owns 128x64 output
  int hi = lane >> 5, lr = lane & 31;

  if (t < 256) sqAs[t] = ws[SQ_OFF + rowBase + t];
  else         sqBs[t - 256] = ws[SQ_OFF + NROWS + colBase + (t - 256)];

  float16 acc[4][2];
#pragma unroll
  for (int i = 0; i < 4; ++i)
#pragma unroll
    for (int j = 0; j < 2; ++j)
#pragma unroll
      for (int r = 0; r < 16; ++r) acc[i][j][r] = 0.f;

  // gload staging: one instr = 64 lanes x 16B = 8 rows x 128B. Lane l -> row r0+(l>>3), slot l&7.
  int grow = lane >> 3;
  int gchunk = (lane & 7) ^ grow;  // inverse-swizzled global chunk (r&7 == grow, r0 % 8 == 0)

  auto STAGE = [&](int buf, int k0) {
    if (BF16SRC) {
#pragma unroll
      for (int j = 0; j < 4; ++j) {
        int r0 = (wave * 4 + j) * 8;
        gload_lds16(Abf + (size_t)(rowBase + r0 + grow) * D + k0 + gchunk * 8, &Ab[buf][r0 * 64]);
        gload_lds16(Bbf + (size_t)(colBase + r0 + grow) * D + k0 + gchunk * 8, &Bb[buf][r0 * 64]);
      }
    } else {
#pragma unroll
      for (int i = 0; i < 4; ++i) {
        int r = (t >> 3) + 64 * i;
        int s = t & 7;
        int slot = (s ^ (r & 7)) << 3;  // ushort units
        const float* pa = &A32[(size_t)(rowBase + r) * D + k0 + s * 8];
        float4 a0 = *reinterpret_cast<const float4*>(pa);
        float4 a1 = *reinterpret_cast<const float4*>(pa + 4);
        *reinterpret_cast<uint4*>(&Ab[buf][r * 64 + slot]) =
            make_uint4(pack2_bf16(a0.x, a0.y), pack2_bf16(a0.z, a0.w),
                       pack2_bf16(a1.x, a1.y), pack2_bf16(a1.z, a1.w));
        const float* pb = &B32[(size_t)(colBase + r) * D + k0 + s * 8];
        float4 b0 = *reinterpret_cast<const float4*>(pb);
        float4 b1 = *reinterpret_cast<const float4*>(pb + 4);
        *reinterpret_cast<uint4*>(&Bb[buf][r * 64 + slot]) =
            make_uint4(pack2_bf16(b0.x, b0.y), pack2_bf16(b0.z, b0.w),
                       pack2_bf16(b1.x, b1.y), pack2_bf16(b1.z, b1.w));
      }
    }
  };

  auto COMPUTE = [&](int buf) {
#pragma unroll
    for (int ks = 0; ks < 4; ++ks) {
      int off = ((ks * 2 + hi) ^ (lr & 7)) << 3;  // same slot expr for all frags (row%8 == lr%8)
      short8 af[4], bf[2];
#pragma unroll
      for (int fr = 0; fr < 4; ++fr)
        af[fr] = *reinterpret_cast<const short8*>(&Ab[buf][(wm * 128 + fr * 32 + lr) * 64 + off]);
#pragma unroll
      for (int fc = 0; fc < 2; ++fc)
        bf[fc] = *reinterpret_cast<const short8*>(&Bb[buf][(wn * 64 + fc * 32 + lr) * 64 + off]);
#pragma unroll
      for (int fr = 0; fr < 4; ++fr)
#pragma unroll
        for (int fc = 0; fc < 2; ++fc)
          acc[fr][fc] = __builtin_amdgcn_mfma_f32_32x32x16_bf16(af[fr], bf[fc], acc[fr][fc], 0, 0, 0);
    }
  };

  STAGE(0, 0);
  __syncthreads();
#pragma unroll
  for (int step = 0; step < 4; ++step) {
    if (step < 3) STAGE((step + 1) & 1, (step + 1) * 64);  // issue next BEFORE compute
    COMPUTE(step & 1);
    __syncthreads();  // drains next-stage vmcnt; all waves done reading current buf
  }

  // Epilogue: C/D map col=lr, row=(reg&3)+8*(reg>>2)+4*hi  [m74/m101]
  float c2 = ws[2];
  float local = 0.f;
#pragma unroll
  for (int fr = 0; fr < 4; ++fr) {
#pragma unroll
    for (int fc = 0; fc < 2; ++fc) {
      float sB = sqBs[wn * 64 + fc * 32 + lr];
#pragma unroll
      for (int r = 0; r < 16; ++r) {
        int rrow = (r & 3) + 8 * (r >> 2) + 4 * hi;
        float dd = sqAs[wm * 128 + fr * 32 + rrow] + sB - 2.0f * acc[fr][fc][r];
        float y = __builtin_amdgcn_exp2f(dd * c2);  // exp(-d/(16 bw))
        float y2 = y * y, y4 = y2 * y2, y8 = y4 * y4, y16 = y8 * y8;
        local += y + y2 + y4 + y8 + y16;
      }
    }
  }
#pragma unroll
  for (int off = 32; off; off >>= 1) local += __shfl_xor(local, off, 64);
  if (lane == 0) red[wave] = local;
  __syncthreads();
  if (t == 0) {
    float s = 0.f;
#pragma unroll
    for (int i = 0; i < 8; ++i) s += red[i];
    ws[CROSSPART + bid] = s;  // plain store, no atomic
  }
}

__global__ __launch_bounds__(256) void finalize_kernel(const float* __restrict__ ws,
                                                       float* __restrict__ out) {
  __shared__ float red[256];
  int t = threadIdx.x;
  red[t] = ws[CROSSPART + t];
  __syncthreads();
#pragma unroll
  for (int s = 128; s > 0; s >>= 1) {
    if (t < s) red[t] += red[t + s];
    __syncthreads();
  }
  if (t == 0) out[0] = -2.0f * (red[0] * (1.0f / 16777216.0f));
}

extern "C" void kernel_launch(void* const* d_in, const int* in_sizes, int n_in,
                              void* d_out, int out_size, void* d_ws, size_t ws_size,
                              hipStream_t stream) {
  const float* src = (const float*)d_in[0];
  const float* tgt = (const float*)d_in[1];
  float* ws = (float*)d_ws;
  float* out = (float*)d_out;
  int useBf16 = ws_size >= (size_t)WS_NEED_FLOATS * sizeof(float);
  const ushort_t* Abf = (const ushort_t*)(ws + ABF_OFF);
  const ushort_t* Bbf = (const ushort_t*)(ws + BBF_OFF);

  // no memset needed: no atomics anywhere; every ws word read is written first
  prep_kernel<<<128, 256, 0, stream>>>(src, tgt, ws, useBf16);
  bw_kernel<<<1, 256, 0, stream>>>(ws);
  if (useBf16)
    cross_kernel<1><<<256, 512, 0, stream>>>(src, tgt, Abf, Bbf, ws);
  else
    cross_kernel<0><<<256, 512, 0, stream>>>(src, tgt, Abf, Bbf, ws);
  finalize_kernel<<<1, 256, 0, stream>>>(ws, out);
}

// Round 7
// 90.239 us; speedup vs baseline: 1.0781x; 1.0691x over previous
//
#include <hip/hip_runtime.h>
#include <hip/hip_bf16.h>

// MMD loss, 3 kernels, atomic-free:
//  K1 prep  (256 blk x 256 thr): bf16 convert, row sq-norms, per-block colsum/S1 partials
//  K2 cross (256 blk x 512 thr): redundant-per-block bw reduce, then 256x256-tile
//                                2-phase double-buffered bf16 MFMA Gram + fused epilogue
//  K3 finalize (1 blk): reduce 256 cross partials -> loss
//
// ws layout (float offsets):
//  SQ_OFF   = 4      sq norms [8192] (0..4095 src, 4096..8191 tgt)
//  S1PART   = 8196   per-block sum-of-norms partials [256]
//  CROSSPART= 8452   per-block cross partials [256]
//  COLPART  = 8708   per-block colsum partials [256][256]
//  ABF_OFF  = 74244  src as bf16 [4096*256]
//  BBF_OFF  = 336388 tgt as bf16 [4096*256]

#define D 256
#define NROWS 4096
#define SQ_OFF 4
#define S1PART 8196
#define CROSSPART 8452
#define COLPART 8708
#define ABF_OFF 74244
#define BBF_OFF 336388
#define WS_NEED_FLOATS 598532

typedef __attribute__((ext_vector_type(8))) short short8;
typedef __attribute__((ext_vector_type(16))) float float16;
typedef unsigned short ushort_t;

__device__ inline unsigned pack2_bf16(float a, float b) {
  unsigned ua = __float_as_uint(a);
  ua += 0x7FFFu + ((ua >> 16) & 1u);
  unsigned ub = __float_as_uint(b);
  ub += 0x7FFFu + ((ub >> 16) & 1u);
  return (ua >> 16) | (ub & 0xFFFF0000u);
}

__device__ inline void gload_lds16(const ushort_t* g, ushort_t* l) {
  __builtin_amdgcn_global_load_lds(
      (const __attribute__((address_space(1))) unsigned int*)g,
      (__attribute__((address_space(3))) unsigned int*)l, 16, 0, 0);
}

// K1: 256 blocks x 256 threads; block handles 32 rows (wave w -> 8 rows).
__global__ __launch_bounds__(256) void prep_kernel(const float* __restrict__ src,
                                                   const float* __restrict__ tgt,
                                                   float* __restrict__ ws,
                                                   int writeBf16) {
  __shared__ float csL[4][256];
  __shared__ float s1L[4];
  ushort_t* Abf = (ushort_t*)(ws + ABF_OFF);
  ushort_t* Bbf = (ushort_t*)(ws + BBF_OFF);
  int t = threadIdx.x;
  int wave = t >> 6, lane = t & 63;
  int rowBase = blockIdx.x * 32 + wave * 8;
  float cs0 = 0.f, cs1 = 0.f, cs2 = 0.f, cs3 = 0.f, s1 = 0.f;
#pragma unroll
  for (int r = 0; r < 8; ++r) {
    int row = rowBase + r;
    int isA = row < NROWS;
    const float* p = isA ? (src + (size_t)row * D) : (tgt + (size_t)(row - NROWS) * D);
    float4 v = reinterpret_cast<const float4*>(p)[lane];
    if (writeBf16) {
      ushort_t* dst = (isA ? Abf + (size_t)row * D : Bbf + (size_t)(row - NROWS) * D) + lane * 4;
      *reinterpret_cast<uint2*>(dst) = make_uint2(pack2_bf16(v.x, v.y), pack2_bf16(v.z, v.w));
    }
    cs0 += v.x; cs1 += v.y; cs2 += v.z; cs3 += v.w;
    float sq = v.x * v.x + v.y * v.y + v.z * v.z + v.w * v.w;
#pragma unroll
    for (int off = 32; off; off >>= 1) sq += __shfl_xor(sq, off, 64);
    if (lane == 0) { ws[SQ_OFF + row] = sq; s1 += sq; }
  }
  csL[wave][lane * 4 + 0] = cs0;
  csL[wave][lane * 4 + 1] = cs1;
  csL[wave][lane * 4 + 2] = cs2;
  csL[wave][lane * 4 + 3] = cs3;
  if (lane == 0) s1L[wave] = s1;
  __syncthreads();
  ws[COLPART + blockIdx.x * 256 + t] = csL[0][t] + csL[1][t] + csL[2][t] + csL[3][t];
  if (t == 0) ws[S1PART + blockIdx.x] = s1L[0] + s1L[1] + s1L[2] + s1L[3];
}

// K2: cross tile 256x256, BK=64, double-buffered 2-phase prefetch.
// LDS row = 64 bf16 = 128B = 8 chunks of 16B; slot s of row r holds chunk s^(r&7).
template <int BF16SRC>
__global__ __launch_bounds__(512, 2) void cross_kernel(const float* __restrict__ A32,
                                                       const float* __restrict__ B32,
                                                       const ushort_t* __restrict__ Abf,
                                                       const ushort_t* __restrict__ Bbf,
                                                       float* __restrict__ ws) {
  __shared__ ushort_t Ab[2][256 * 64];  // 2 x 32 KB
  __shared__ ushort_t Bb[2][256 * 64];  // 2 x 32 KB
  __shared__ float sqAs[256], sqBs[256];
  __shared__ float colhalf[2][256];
  __shared__ float redq[256];
  __shared__ float s1sh[256];
  __shared__ float red[8];
  __shared__ float c2sh;
  int t = threadIdx.x;
  int bid = blockIdx.x;

  // ---- phase B: redundant per-block bandwidth computation (all from L2) ----
  {
    int col = t & 255, half = t >> 8;
    float part = 0.f;
#pragma unroll 8
    for (int b = 0; b < 128; ++b) part += ws[COLPART + (size_t)(half * 128 + b) * 256 + col];
    colhalf[half][col] = part;
    if (t < 256) s1sh[t] = ws[S1PART + t];
  }
  __syncthreads();
  if (t < 256) { float c = colhalf[0][t] + colhalf[1][t]; redq[t] = c * c; }
  __syncthreads();
#pragma unroll
  for (int s = 128; s > 0; s >>= 1) {
    if (t < s) { redq[t] += redq[t + s]; s1sh[t] += s1sh[t + s]; }
    __syncthreads();
  }
  if (t == 0) {
    double n = 8192.0;
    double sumL2 = 2.0 * n * (double)s1sh[0] - 2.0 * (double)redq[0];
    double bwv = sumL2 / (n * n - n) / 4.0;  // KERNEL_MUL^(KERNEL_NUM//2) = 4
    c2sh = (float)(-1.4426950408889634 / (16.0 * bwv));
  }

  // ---- phase C: cross Gram ----
  // XCD-aware: 16x16 tile grid; each XCD owns a 4x8 rectangle
  int xcd = bid & 7, idx = bid >> 3;
  int bi = (xcd >> 1) * 4 + (idx >> 3);
  int bj = (xcd & 1) * 8 + (idx & 7);
  int rowBase = bi * 256, colBase = bj * 256;
  int wave = t >> 6, lane = t & 63;
  int wm = wave >> 2, wn = wave & 3;   // 2x4 wave grid; wave owns 128x64 output
  int hi = lane >> 5, lr = lane & 31;

  if (t < 256) sqAs[t] = ws[SQ_OFF + rowBase + t];
  else         sqBs[t - 256] = ws[SQ_OFF + NROWS + colBase + (t - 256)];

  float16 acc[4][2];
#pragma unroll
  for (int i = 0; i < 4; ++i)
#pragma unroll
    for (int j = 0; j < 2; ++j)
#pragma unroll
      for (int r = 0; r < 16; ++r) acc[i][j][r] = 0.f;

  int grow = lane >> 3;
  int gchunk = (lane & 7) ^ grow;  // inverse-swizzled global chunk

  auto STAGE = [&](int buf, int k0) {
    if (BF16SRC) {
#pragma unroll
      for (int j = 0; j < 4; ++j) {
        int r0 = (wave * 4 + j) * 8;
        gload_lds16(Abf + (size_t)(rowBase + r0 + grow) * D + k0 + gchunk * 8, &Ab[buf][r0 * 64]);
        gload_lds16(Bbf + (size_t)(colBase + r0 + grow) * D + k0 + gchunk * 8, &Bb[buf][r0 * 64]);
      }
    } else {
#pragma unroll
      for (int i = 0; i < 4; ++i) {
        int r = (t >> 3) + 64 * i;
        int s = t & 7;
        int slot = (s ^ (r & 7)) << 3;
        const float* pa = &A32[(size_t)(rowBase + r) * D + k0 + s * 8];
        float4 a0 = *reinterpret_cast<const float4*>(pa);
        float4 a1 = *reinterpret_cast<const float4*>(pa + 4);
        *reinterpret_cast<uint4*>(&Ab[buf][r * 64 + slot]) =
            make_uint4(pack2_bf16(a0.x, a0.y), pack2_bf16(a0.z, a0.w),
                       pack2_bf16(a1.x, a1.y), pack2_bf16(a1.z, a1.w));
        const float* pb = &B32[(size_t)(colBase + r) * D + k0 + s * 8];
        float4 b0 = *reinterpret_cast<const float4*>(pb);
        float4 b1 = *reinterpret_cast<const float4*>(pb + 4);
        *reinterpret_cast<uint4*>(&Bb[buf][r * 64 + slot]) =
            make_uint4(pack2_bf16(b0.x, b0.y), pack2_bf16(b0.z, b0.w),
                       pack2_bf16(b1.x, b1.y), pack2_bf16(b1.z, b1.w));
      }
    }
  };

  auto COMPUTE = [&](int buf) {
#pragma unroll
    for (int ks = 0; ks < 4; ++ks) {
      int off = ((ks * 2 + hi) ^ (lr & 7)) << 3;
      short8 af[4], bf[2];
#pragma unroll
      for (int fr = 0; fr < 4; ++fr)
        af[fr] = *reinterpret_cast<const short8*>(&Ab[buf][(wm * 128 + fr * 32 + lr) * 64 + off]);
#pragma unroll
      for (int fc = 0; fc < 2; ++fc)
        bf[fc] = *reinterpret_cast<const short8*>(&Bb[buf][(wn * 64 + fc * 32 + lr) * 64 + off]);
#pragma unroll
      for (int fr = 0; fr < 4; ++fr)
#pragma unroll
        for (int fc = 0; fc < 2; ++fc)
          acc[fr][fc] = __builtin_amdgcn_mfma_f32_32x32x16_bf16(af[fr], bf[fc], acc[fr][fc], 0, 0, 0);
    }
  };

  STAGE(0, 0);
  __syncthreads();
#pragma unroll
  for (int step = 0; step < 4; ++step) {
    if (step < 3) STAGE((step + 1) & 1, (step + 1) * 64);  // issue next BEFORE compute
    COMPUTE(step & 1);
    __syncthreads();
  }

  // Epilogue: C/D map col=lr, row=(reg&3)+8*(reg>>2)+4*hi  [m74/m101]
  float c2 = c2sh;
  float local = 0.f;
#pragma unroll
  for (int fr = 0; fr < 4; ++fr) {
#pragma unroll
    for (int fc = 0; fc < 2; ++fc) {
      float sB = sqBs[wn * 64 + fc * 32 + lr];
#pragma unroll
      for (int r = 0; r < 16; ++r) {
        int rrow = (r & 3) + 8 * (r >> 2) + 4 * hi;
        float dd = sqAs[wm * 128 + fr * 32 + rrow] + sB - 2.0f * acc[fr][fc][r];
        float y = __builtin_amdgcn_exp2f(dd * c2);  // exp(-d/(16 bw_base))
        float y2 = y * y, y4 = y2 * y2, y8 = y4 * y4, y16 = y8 * y8;
        local += y + y2 + y4 + y8 + y16;
      }
    }
  }
#pragma unroll
  for (int off = 32; off; off >>= 1) local += __shfl_xor(local, off, 64);
  if (lane == 0) red[wave] = local;
  __syncthreads();
  if (t == 0) {
    float s = 0.f;
#pragma unroll
    for (int i = 0; i < 8; ++i) s += red[i];
    ws[CROSSPART + bid] = s;  // plain store, no atomic
  }
}

__global__ __launch_bounds__(256) void finalize_kernel(const float* __restrict__ ws,
                                                       float* __restrict__ out) {
  __shared__ float red[256];
  int t = threadIdx.x;
  red[t] = ws[CROSSPART + t];
  __syncthreads();
#pragma unroll
  for (int s = 128; s > 0; s >>= 1) {
    if (t < s) red[t] += red[t + s];
    __syncthreads();
  }
  if (t == 0) out[0] = -2.0f * (red[0] * (1.0f / 16777216.0f));
}

extern "C" void kernel_launch(void* const* d_in, const int* in_sizes, int n_in,
                              void* d_out, int out_size, void* d_ws, size_t ws_size,
                              hipStream_t stream) {
  const float* src = (const float*)d_in[0];
  const float* tgt = (const float*)d_in[1];
  float* ws = (float*)d_ws;
  float* out = (float*)d_out;
  int useBf16 = ws_size >= (size_t)WS_NEED_FLOATS * sizeof(float);
  const ushort_t* Abf = (const ushort_t*)(ws + ABF_OFF);
  const ushort_t* Bbf = (const ushort_t*)(ws + BBF_OFF);

  prep_kernel<<<256, 256, 0, stream>>>(src, tgt, ws, useBf16);
  if (useBf16)
    cross_kernel<1><<<256, 512, 0, stream>>>(src, tgt, Abf, Bbf, ws);
  else
    cross_kernel<0><<<256, 512, 0, stream>>>(src, tgt, Abf, Bbf, ws);
  finalize_kernel<<<1, 256, 0, stream>>>(ws, out);
}

// Round 8
// 88.564 us; speedup vs baseline: 1.0985x; 1.0189x over previous
//
#include <hip/hip_runtime.h>
#include <hip/hip_bf16.h>

// MMD loss, 3 kernels, atomic-free:
//  K1 prep  (256 blk x 256 thr): bf16 convert, row sq-norms, per-block colsum/S1 partials
//  K2 cross (256 blk x 512 thr): per-block bw reduce, then 256x256-tile bf16 MFMA Gram
//       with counted-vmcnt double-buffer pipeline (T4) + setprio (T5) + fused epilogue
//  K3 finalize (1 blk): reduce 256 cross partials -> loss
//
// ws layout (float offsets):
//  SQ_OFF   = 4      sq norms [8192] (0..4095 src, 4096..8191 tgt)
//  S1PART   = 8196   per-block sum-of-norms partials [256]
//  CROSSPART= 8452   per-block cross partials [256]
//  COLPART  = 8708   per-block colsum partials [256][256]
//  ABF_OFF  = 74244  src as bf16 [4096*256]
//  BBF_OFF  = 336388 tgt as bf16 [4096*256]

#define D 256
#define NROWS 4096
#define SQ_OFF 4
#define S1PART 8196
#define CROSSPART 8452
#define COLPART 8708
#define ABF_OFF 74244
#define BBF_OFF 336388
#define WS_NEED_FLOATS 598532

typedef __attribute__((ext_vector_type(8))) short short8;
typedef __attribute__((ext_vector_type(16))) float float16;
typedef unsigned short ushort_t;

__device__ inline unsigned pack2_bf16(float a, float b) {
  unsigned ua = __float_as_uint(a);
  ua += 0x7FFFu + ((ua >> 16) & 1u);
  unsigned ub = __float_as_uint(b);
  ub += 0x7FFFu + ((ub >> 16) & 1u);
  return (ua >> 16) | (ub & 0xFFFF0000u);
}

__device__ inline void gload_lds16(const ushort_t* g, ushort_t* l) {
  __builtin_amdgcn_global_load_lds(
      (const __attribute__((address_space(1))) unsigned int*)g,
      (__attribute__((address_space(3))) unsigned int*)l, 16, 0, 0);
}

// K1: 256 blocks x 256 threads; block handles 32 rows (wave w -> 8 rows).
__global__ __launch_bounds__(256) void prep_kernel(const float* __restrict__ src,
                                                   const float* __restrict__ tgt,
                                                   float* __restrict__ ws,
                                                   int writeBf16) {
  __shared__ float csL[4][256];
  __shared__ float s1L[4];
  ushort_t* Abf = (ushort_t*)(ws + ABF_OFF);
  ushort_t* Bbf = (ushort_t*)(ws + BBF_OFF);
  int t = threadIdx.x;
  int wave = t >> 6, lane = t & 63;
  int rowBase = blockIdx.x * 32 + wave * 8;
  float cs0 = 0.f, cs1 = 0.f, cs2 = 0.f, cs3 = 0.f, s1 = 0.f;
#pragma unroll
  for (int r = 0; r < 8; ++r) {
    int row = rowBase + r;
    int isA = row < NROWS;
    const float* p = isA ? (src + (size_t)row * D) : (tgt + (size_t)(row - NROWS) * D);
    float4 v = reinterpret_cast<const float4*>(p)[lane];
    if (writeBf16) {
      ushort_t* dst = (isA ? Abf + (size_t)row * D : Bbf + (size_t)(row - NROWS) * D) + lane * 4;
      *reinterpret_cast<uint2*>(dst) = make_uint2(pack2_bf16(v.x, v.y), pack2_bf16(v.z, v.w));
    }
    cs0 += v.x; cs1 += v.y; cs2 += v.z; cs3 += v.w;
    float sq = v.x * v.x + v.y * v.y + v.z * v.z + v.w * v.w;
#pragma unroll
    for (int off = 32; off; off >>= 1) sq += __shfl_xor(sq, off, 64);
    if (lane == 0) { ws[SQ_OFF + row] = sq; s1 += sq; }
  }
  csL[wave][lane * 4 + 0] = cs0;
  csL[wave][lane * 4 + 1] = cs1;
  csL[wave][lane * 4 + 2] = cs2;
  csL[wave][lane * 4 + 3] = cs3;
  if (lane == 0) s1L[wave] = s1;
  __syncthreads();
  ws[COLPART + blockIdx.x * 256 + t] = csL[0][t] + csL[1][t] + csL[2][t] + csL[3][t];
  if (t == 0) ws[S1PART + blockIdx.x] = s1L[0] + s1L[1] + s1L[2] + s1L[3];
}

// K2: cross tile 256x256, BK=64, counted-vmcnt double-buffered pipeline.
// LDS row = 64 bf16 = 128B = 8 chunks of 16B; slot s of row r holds chunk s^(r&7).
template <int BF16SRC>
__global__ __launch_bounds__(512, 2) void cross_kernel(const float* __restrict__ A32,
                                                       const float* __restrict__ B32,
                                                       const ushort_t* __restrict__ Abf,
                                                       const ushort_t* __restrict__ Bbf,
                                                       float* __restrict__ ws) {
  __shared__ ushort_t Ab[2][256 * 64];  // 2 x 32 KB
  __shared__ ushort_t Bb[2][256 * 64];  // 2 x 32 KB
  __shared__ float sqAs[256], sqBs[256];
  __shared__ float colhalf[2][256];
  __shared__ float redq[256];
  __shared__ float s1sh[256];
  __shared__ float red[8];
  __shared__ float c2sh;
  int t = threadIdx.x;
  int bid = blockIdx.x;

  // tile indices first (needed by the early prefetch)
  int xcd = bid & 7, idx = bid >> 3;
  int bi = (xcd >> 1) * 4 + (idx >> 3);
  int bj = (xcd & 1) * 8 + (idx & 7);
  int rowBase = bi * 256, colBase = bj * 256;
  int wave = t >> 6, lane = t & 63;
  int wm = wave >> 2, wn = wave & 3;   // 2x4 wave grid; wave owns 128x64 output
  int hi = lane >> 5, lr = lane & 31;

  int grow = lane >> 3;
  int gchunk = (lane & 7) ^ grow;  // inverse-swizzled global chunk

  auto STAGE = [&](int buf, int k0) {
    if (BF16SRC) {
#pragma unroll
      for (int j = 0; j < 4; ++j) {
        int r0 = (wave * 4 + j) * 8;
        gload_lds16(Abf + (size_t)(rowBase + r0 + grow) * D + k0 + gchunk * 8, &Ab[buf][r0 * 64]);
        gload_lds16(Bbf + (size_t)(colBase + r0 + grow) * D + k0 + gchunk * 8, &Bb[buf][r0 * 64]);
      }
    } else {
#pragma unroll
      for (int i = 0; i < 4; ++i) {
        int r = (t >> 3) + 64 * i;
        int s = t & 7;
        int slot = (s ^ (r & 7)) << 3;
        const float* pa = &A32[(size_t)(rowBase + r) * D + k0 + s * 8];
        float4 a0 = *reinterpret_cast<const float4*>(pa);
        float4 a1 = *reinterpret_cast<const float4*>(pa + 4);
        *reinterpret_cast<uint4*>(&Ab[buf][r * 64 + slot]) =
            make_uint4(pack2_bf16(a0.x, a0.y), pack2_bf16(a0.z, a0.w),
                       pack2_bf16(a1.x, a1.y), pack2_bf16(a1.z, a1.w));
        const float* pb = &B32[(size_t)(colBase + r) * D + k0 + s * 8];
        float4 b0 = *reinterpret_cast<const float4*>(pb);
        float4 b1 = *reinterpret_cast<const float4*>(pb + 4);
        *reinterpret_cast<uint4*>(&Bb[buf][r * 64 + slot]) =
            make_uint4(pack2_bf16(b0.x, b0.y), pack2_bf16(b0.z, b0.w),
                       pack2_bf16(b1.x, b1.y), pack2_bf16(b1.z, b1.w));
      }
    }
  };

  // issue K-tile 0 staging EARLY: its L2 latency hides under phase B
  STAGE(0, 0);

  // ---- phase B: per-block bandwidth computation (reads COLPART from L2/L3) ----
  {
    int col = t & 255, half = t >> 8;
    const float* cp = ws + COLPART + (size_t)half * 128 * 256 + col;
    float part = 0.f;
#pragma unroll 32
    for (int b = 0; b < 128; ++b) part += cp[(size_t)b * 256];
    colhalf[half][col] = part;
    if (t < 256) s1sh[t] = ws[S1PART + t];
  }
  __syncthreads();
  if (t < 256) { float c = colhalf[0][t] + colhalf[1][t]; redq[t] = c * c; }
  // stage sq norms for the epilogue while redq settles
  if (t < 256) sqAs[t] = ws[SQ_OFF + rowBase + t];
  else         sqBs[t - 256] = ws[SQ_OFF + NROWS + colBase + (t - 256)];
  __syncthreads();
  if (t < 64) {
    float r = redq[t] + redq[t + 64] + redq[t + 128] + redq[t + 192];
    float s = s1sh[t] + s1sh[t + 64] + s1sh[t + 128] + s1sh[t + 192];
#pragma unroll
    for (int off = 32; off; off >>= 1) {
      r += __shfl_xor(r, off, 64);
      s += __shfl_xor(s, off, 64);
    }
    if (t == 0) {
      double n = 8192.0;
      double sumL2 = 2.0 * n * (double)s - 2.0 * (double)r;
      double bwv = sumL2 / (n * n - n) / 4.0;  // KERNEL_MUL^(KERNEL_NUM//2) = 4
      c2sh = (float)(-1.4426950408889634 / (16.0 * bwv));
    }
  }

  float16 acc[4][2];
#pragma unroll
  for (int i = 0; i < 4; ++i)
#pragma unroll
    for (int j = 0; j < 2; ++j)
#pragma unroll
      for (int r = 0; r < 16; ++r) acc[i][j][r] = 0.f;

  auto COMPUTE = [&](int buf) {
#pragma unroll
    for (int ks = 0; ks < 4; ++ks) {
      int off = ((ks * 2 + hi) ^ (lr & 7)) << 3;
      short8 af[4], bf[2];
#pragma unroll
      for (int fr = 0; fr < 4; ++fr)
        af[fr] = *reinterpret_cast<const short8*>(&Ab[buf][(wm * 128 + fr * 32 + lr) * 64 + off]);
#pragma unroll
      for (int fc = 0; fc < 2; ++fc)
        bf[fc] = *reinterpret_cast<const short8*>(&Bb[buf][(wn * 64 + fc * 32 + lr) * 64 + off]);
      __builtin_amdgcn_s_setprio(1);
#pragma unroll
      for (int fr = 0; fr < 4; ++fr)
#pragma unroll
        for (int fc = 0; fc < 2; ++fc)
          acc[fr][fc] = __builtin_amdgcn_mfma_f32_32x32x16_bf16(af[fr], bf[fc], acc[fr][fc], 0, 0, 0);
      __builtin_amdgcn_s_setprio(0);
    }
  };

  __syncthreads();  // phase B LDS visible; stage-0 drained (completed during phase B)

  if (BF16SRC) {
    // T4 counted-vmcnt pipeline: stage k+1's 8 gloads stay in flight through
    // both barriers and COMPUTE(k); vmcnt never drains to 0 until the last step.
#pragma unroll
    for (int step = 0; step < 4; ++step) {
      if (step < 3) STAGE((step + 1) & 1, (step + 1) * 64);   // 8 gloads
      if (step < 3) asm volatile("s_waitcnt vmcnt(8)" ::: "memory");
      else          asm volatile("s_waitcnt vmcnt(0)" ::: "memory");
      __builtin_amdgcn_s_barrier();   // all waves: stage(step) landed
      COMPUTE(step & 1);
      if (step < 3) __builtin_amdgcn_s_barrier();  // buf free for stage(step+2)
    }
  } else {
#pragma unroll
    for (int step = 0; step < 4; ++step) {
      if (step < 3) STAGE((step + 1) & 1, (step + 1) * 64);
      COMPUTE(step & 1);
      __syncthreads();
    }
  }

  // Epilogue: C/D map col=lr, row=(reg&3)+8*(reg>>2)+4*hi  [m74/m101]
  float c2 = c2sh;
  float local = 0.f;
#pragma unroll
  for (int fr = 0; fr < 4; ++fr) {
#pragma unroll
    for (int fc = 0; fc < 2; ++fc) {
      float sB = sqBs[wn * 64 + fc * 32 + lr];
#pragma unroll
      for (int r = 0; r < 16; ++r) {
        int rrow = (r & 3) + 8 * (r >> 2) + 4 * hi;
        float dd = sqAs[wm * 128 + fr * 32 + rrow] + sB - 2.0f * acc[fr][fc][r];
        float y = __builtin_amdgcn_exp2f(dd * c2);  // exp(-d/(16 bw_base))
        float y2 = y * y, y4 = y2 * y2, y8 = y4 * y4, y16 = y8 * y8;
        local += y + y2 + y4 + y8 + y16;
      }
    }
  }
#pragma unroll
  for (int off = 32; off; off >>= 1) local += __shfl_xor(local, off, 64);
  if (lane == 0) red[wave] = local;
  __syncthreads();
  if (t == 0) {
    float s = 0.f;
#pragma unroll
    for (int i = 0; i < 8; ++i) s += red[i];
    ws[CROSSPART + bid] = s;  // plain store, no atomic
  }
}

__global__ __launch_bounds__(256) void finalize_kernel(const float* __restrict__ ws,
                                                       float* __restrict__ out) {
  __shared__ float red[256];
  int t = threadIdx.x;
  red[t] = ws[CROSSPART + t];
  __syncthreads();
#pragma unroll
  for (int s = 128; s > 0; s >>= 1) {
    if (t < s) red[t] += red[t + s];
    __syncthreads();
  }
  if (t == 0) out[0] = -2.0f * (red[0] * (1.0f / 16777216.0f));
}

extern "C" void kernel_launch(void* const* d_in, const int* in_sizes, int n_in,
                              void* d_out, int out_size, void* d_ws, size_t ws_size,
                              hipStream_t stream) {
  const float* src = (const float*)d_in[0];
  const float* tgt = (const float*)d_in[1];
  float* ws = (float*)d_ws;
  float* out = (float*)d_out;
  int useBf16 = ws_size >= (size_t)WS_NEED_FLOATS * sizeof(float);
  const ushort_t* Abf = (const ushort_t*)(ws + ABF_OFF);
  const ushort_t* Bbf = (const ushort_t*)(ws + BBF_OFF);

  prep_kernel<<<256, 256, 0, stream>>>(src, tgt, ws, useBf16);
  if (useBf16)
    cross_kernel<1><<<256, 512, 0, stream>>>(src, tgt, Abf, Bbf, ws);
  else
    cross_kernel<0><<<256, 512, 0, stream>>>(src, tgt, Abf, Bbf, ws);
  finalize_kernel<<<1, 256, 0, stream>>>(ws, out);
}